// Round 6
// baseline (494.735 us; speedup 1.0000x reference)
//
#include <hip/hip_runtime.h>

#define L_AUDIO 15360000
#define PADLEN  15361024   // L + 1024
#define FRAMES  30001
#define CHP     513        // channel pairs (real k, imag k+513)
#define NBAS    (1026*1024)

#define BM  256            // frames per block
#define BNP 128            // channel pairs per block (256 basis rows)
#define BK  64
#define NKT 16             // 1024 / BK
#define NCB 5              // ceil(513/128)
#define NFB 118            // ceil(30001/256)
#define NWG (NFB*NCB)      // 590

typedef __attribute__((ext_vector_type(8))) short short8;
typedef __attribute__((ext_vector_type(4))) float f32x4;

__device__ __forceinline__ unsigned short f2bf(float f) {
    unsigned int u = __float_as_uint(f);
    u += 0x7fffu + ((u >> 16) & 1u);   // round-to-nearest-even
    return (unsigned short)(u >> 16);
}

__global__ __launch_bounds__(256) void prep_pad_k(const float* __restrict__ a,
                                                  unsigned short* __restrict__ pad) {
    long i = (long)blockIdx.x * blockDim.x + threadIdx.x;   // [0, PADLEN/4)
    long p0 = i * 4;
    if (p0 >= 512 && p0 + 4 <= 512 + L_AUDIO) {
        const float4 v = *reinterpret_cast<const float4*>(a + (p0 - 512));
        ushort4 o;
        o.x = f2bf(v.x); o.y = f2bf(v.y); o.z = f2bf(v.z); o.w = f2bf(v.w);
        *reinterpret_cast<ushort4*>(pad + p0) = o;
    } else {
        for (int j = 0; j < 4; ++j) {
            long p = p0 + j;
            long src = p - 512;
            if (p < 512) src = 512 - p;
            else if (src >= L_AUDIO) src = 2L*L_AUDIO - 2 - src;
            pad[p] = f2bf(a[src]);
        }
    }
}

__global__ __launch_bounds__(256) void prep_bas_k(const float* __restrict__ b,
                                                  unsigned short* __restrict__ o) {
    long i = (long)blockIdx.x * blockDim.x + threadIdx.x;
    const float4 v = *reinterpret_cast<const float4*>(b + i * 4);
    ushort4 u;
    u.x = f2bf(v.x); u.y = f2bf(v.y); u.z = f2bf(v.z); u.w = f2bf(v.w);
    *reinterpret_cast<ushort4*>(o + i * 4) = u;
}

// 256(frames) x 256(basis rows = 128 pairs) x K=64 tiles, 8 waves (2M x 4N),
// per-wave 128x64. B rows reordered in 16-row frags (real/imag interleaved)
// so the power epilogue stays wave-local. LDS XOR-swizzle per rule 21.
// SINGLE-buffered 64 KB LDS -> 2 blocks/CU (16 waves/CU): one block's
// staging stall (vmcnt(0)) is covered by the co-resident block's MFMA phase
// (m114 cross-block overlap). m97-style 2-barrier tile loop.
__global__ __launch_bounds__(512, 4) void stft_gemm(const unsigned short* __restrict__ pad,
                                                    const unsigned short* __restrict__ bas,
                                                    float* __restrict__ out) {
    __shared__ unsigned short lsA[BM * BK];   // 32 KB
    __shared__ unsigned short lsB[BM * BK];   // 32 KB

    const int tid  = threadIdx.x;
    const int w    = tid >> 6;
    const int lane = tid & 63;
    const int l15  = lane & 15;
    const int lk   = lane >> 4;
    const int wm   = w >> 2;          // 0..1 (M half)
    const int wn   = w & 3;           // 0..3 (N quarter)

    // bijective XCD-chunked remap (m204): NWG=590 = 8*73+6
    const int orig = blockIdx.x;
    const int xcd  = orig & 7;
    const int lid  = orig >> 3;
    const int wg   = (xcd < 6 ? xcd * 74 : 6 * 74 + (xcd - 6) * 73) + lid;
    const int fb   = wg / NCB;
    const int cb   = wg - fb * NCB;
    const long t0  = (long)fb * BM;
    const int  c0  = cb * BNP;

    // Per-thread staging sources (chunk c = j*512 + tid of 2048 16B-chunks).
    const unsigned short* aS[4];
    const unsigned short* bS[4];
    #pragma unroll
    for (int j = 0; j < 4; ++j) {
        const int c   = j * 512 + tid;
        const int row = c >> 3;                  // 0..255
        const int sc  = (c & 7) ^ (row & 7);     // pre-swizzled source chunk
        long tf = t0 + row; if (tf > FRAMES - 1) tf = FRAMES - 1;
        aS[j] = pad + tf * 512 + sc * 8;
        const int g = row >> 4;                  // 16-row frag id
        int ch = c0 + (g >> 1) * 16 + (row & 15); if (ch > 512) ch = 512;
        const long brow = (g & 1) ? (long)(513 + ch) : (long)ch;
        bS[j] = bas + brow * 1024 + sc * 8;
    }

    f32x4 acc[8][4];
    #pragma unroll
    for (int a = 0; a < 8; ++a)
        #pragma unroll
        for (int b = 0; b < 4; ++b)
            acc[a][b] = (f32x4){0.f, 0.f, 0.f, 0.f};

    const int wmBase = wm * 128;
    const int wnBase = wn * 64;

#define GLD(dst, src) __builtin_amdgcn_global_load_lds( \
        (const __attribute__((address_space(1))) unsigned int*)(src), \
        (__attribute__((address_space(3))) unsigned int*)(dst), 16, 0, 0)

#define LDSREAD(basePtr, r, S) \
    (*reinterpret_cast<const short8*>(reinterpret_cast<const char*>(basePtr) \
        + (r) * 128 + ((((S) * 4 + lk) ^ ((r) & 7)) << 4)))

    for (int t = 0; t < NKT; ++t) {
        const int ko = t * BK;
        if (t) __syncthreads();                  // all reads of prev tile retired
        #pragma unroll
        for (int j = 0; j < 4; ++j) {
            GLD(&lsA[(j * 512 + tid) * 8], aS[j] + ko);
            GLD(&lsB[(j * 512 + tid) * 8], bS[j] + ko);
        }
        asm volatile("s_waitcnt vmcnt(0)" ::: "memory");
        __builtin_amdgcn_s_barrier();
        asm volatile("" ::: "memory");

        // 24 ds_read + 64 MFMA per wave; compiler's fine-grained lgkmcnt
        // scheduling overlaps LDS and matrix pipes within the tile.
        #pragma unroll
        for (int S = 0; S < 2; ++S) {
            short8 bf[4];
            #pragma unroll
            for (int b = 0; b < 4; ++b)
                bf[b] = LDSREAD(lsB, wnBase + b * 16 + l15, S);
            #pragma unroll
            for (int mq = 0; mq < 8; ++mq) {
                short8 af = LDSREAD(lsA, wmBase + mq * 16 + l15, S);
                #pragma unroll
                for (int b = 0; b < 4; ++b)
                    acc[mq][b] = __builtin_amdgcn_mfma_f32_16x16x32_bf16(
                        af, bf[b], acc[mq][b], 0, 0, 0);
            }
        }
        asm volatile("" ::: "memory");
    }

    // Epilogue: out[ch][t] = re^2 + im^2
    // D layout: col = lane&15 (pair), row = lk*4 + reg (frame)
    const int tb = (int)t0 + wmBase;
    #pragma unroll
    for (int a = 0; a < 8; ++a) {
        #pragma unroll
        for (int q = 0; q < 2; ++q) {
            const int ch = c0 + wn * 32 + q * 16 + l15;
            if (ch >= CHP) continue;
            const long ob = (long)ch * FRAMES;
            const int tv = tb + a * 16 + lk * 4;
            const f32x4 re = acc[a][q * 2];
            const f32x4 im = acc[a][q * 2 + 1];
            if (tv + 3 < FRAMES) {
                #pragma unroll
                for (int r = 0; r < 4; ++r)
                    out[ob + tv + r] = re[r] * re[r] + im[r] * im[r];
            } else {
                #pragma unroll
                for (int r = 0; r < 4; ++r)
                    if (tv + r < FRAMES)
                        out[ob + tv + r] = re[r] * re[r] + im[r] * im[r];
            }
        }
    }
}

extern "C" void kernel_launch(void* const* d_in, const int* in_sizes, int n_in,
                              void* d_out, int out_size, void* d_ws, size_t ws_size,
                              hipStream_t stream) {
    const float* audio = (const float*)d_in[0];
    const float* basis = (const float*)d_in[1];
    float* out = (float*)d_out;

    unsigned short* pad = (unsigned short*)d_ws;
    unsigned short* bas = pad + PADLEN;

    prep_pad_k<<<PADLEN / 4 / 256, 256, 0, stream>>>(audio, pad);
    prep_bas_k<<<NBAS / 4 / 256, 256, 0, stream>>>(basis, bas);

    stft_gemm<<<NWG, 512, 0, stream>>>(pad, bas, out);
}

// Round 9
// 119.664 us; speedup vs baseline: 4.1344x; 4.1344x over previous
//
#include <hip/hip_runtime.h>

#define L_AUDIO 15360000
#define PADLEN  15361024   // 512*30000 + 1024 : exactly covers frames 0..30000
#define FRAMES  30001
#define NBAS    (1026*1024)

#define BM   256           // frames per GEMM block
#define BK   64
#define NKT  16            // 1024 / BK
#define NGEMM 472          // 118 frame-blocks x 4 channel-blocks (pairs 0..511)
#define NWG   504          // = 8 * 63 : exactly 2 rounds of 256, bijective XCD chunk

typedef __attribute__((ext_vector_type(8))) short short8;
typedef __attribute__((ext_vector_type(4))) float f32x4;

__device__ __forceinline__ unsigned short f2bf(float f) {
    unsigned int u = __float_as_uint(f);
    u += 0x7fffu + ((u >> 16) & 1u);   // round-to-nearest-even
    return (unsigned short)(u >> 16);
}

__global__ __launch_bounds__(256) void prep_pad_k(const float* __restrict__ a,
                                                  unsigned short* __restrict__ pad) {
    long i = (long)blockIdx.x * blockDim.x + threadIdx.x;   // [0, PADLEN/4)
    long p0 = i * 4;
    if (p0 >= 512 && p0 + 4 <= 512 + L_AUDIO) {
        const float4 v = *reinterpret_cast<const float4*>(a + (p0 - 512));
        ushort4 o;
        o.x = f2bf(v.x); o.y = f2bf(v.y); o.z = f2bf(v.z); o.w = f2bf(v.w);
        *reinterpret_cast<ushort4*>(pad + p0) = o;
    } else {
        for (int j = 0; j < 4; ++j) {
            long p = p0 + j;
            long src = p - 512;
            if (p < 512) src = 512 - p;
            else if (src >= L_AUDIO) src = 2L*L_AUDIO - 2 - src;
            pad[p] = f2bf(a[src]);
        }
    }
}

__global__ __launch_bounds__(256) void prep_bas_k(const float* __restrict__ b,
                                                  unsigned short* __restrict__ o) {
    long i = (long)blockIdx.x * blockDim.x + threadIdx.x;
    const float4 v = *reinterpret_cast<const float4*>(b + i * 4);
    ushort4 u;
    u.x = f2bf(v.x); u.y = f2bf(v.y); u.z = f2bf(v.z); u.w = f2bf(v.w);
    *reinterpret_cast<ushort4*>(o + i * 4) = u;
}

// GEMM blocks: 256 frames x 256 basis rows (128 pairs) x K=64 tiles, 8 waves
// (2M x 4N), per-wave 128x64. ONE __syncthreads() per tile (drains own stage
// GLDs via vmcnt(0), rendezvous, AND compiler memory fence). Staging for tile
// t+1 issued early in tile t's body (full tile of MFMA latency cover) into the
// opposite buffer. Fragment pipeline: afA (m-frags 0-3), afB (m-frags 4-7),
// bf; reads for the next cluster issue before the current cluster's MFMAs.
// INVARIANT (R7/R8 bug): afA ALWAYS accumulates into acc[0..3] (MQ=0), afB
// ALWAYS into acc[4..7] (MQ=1); the S index only selects the K-slice.
// Nyquist blocks (wg>=472) compute pair 512 on the VALU in fp32.
__global__ __launch_bounds__(512, 2) void stft_gemm(const unsigned short* __restrict__ pad,
                                                    const unsigned short* __restrict__ bas,
                                                    const float* __restrict__ bas32,
                                                    float* __restrict__ out) {
    __shared__ unsigned short lsA[2][BM * BK];   // 2 x 32 KB
    __shared__ unsigned short lsB[2][BM * BK];   // 2 x 32 KB

    const int tid = threadIdx.x;

    // bijective XCD-chunked remap: 504 = 8 * 63
    const int bid = blockIdx.x;
    const int wg  = (bid & 7) * 63 + (bid >> 3);

    if (wg >= NGEMM) {
        // ---- Nyquist path: out[512][f] for pair 512, fp32 VALU ----
        const int k    = wg - NGEMM;
        const int base = k * 938;                       // 32*938 >= 30001
        const int lim  = (base + 938 < FRAMES) ? base + 938 : FRAMES;
        const float* br = bas32 + (long)512  * 1024;
        const float* bi = bas32 + (long)1025 * 1024;
        float* o512 = out + (long)512 * FRAMES;
        #pragma unroll
        for (int rep = 0; rep < 2; ++rep) {
            const int f = base + rep * 512 + tid;
            if (f < lim) {
                const unsigned short* ap = pad + (long)f * 512;
                float re = 0.f, im = 0.f;
                for (int n = 0; n < 1024; n += 8) {
                    short8 a8 = *reinterpret_cast<const short8*>(ap + n);
                    #pragma unroll
                    for (int u = 0; u < 8; ++u) {
                        float av = __uint_as_float(((unsigned)(unsigned short)a8[u]) << 16);
                        re = fmaf(av, br[n + u], re);
                        im = fmaf(av, bi[n + u], im);
                    }
                }
                o512[f] = re * re + im * im;
            }
        }
        return;
    }

    const int w    = tid >> 6;
    const int lane = tid & 63;
    const int l15  = lane & 15;
    const int lk   = lane >> 4;
    const int wm   = w >> 2;          // 0..1 (M half)
    const int wn   = w & 3;           // 0..3 (N quarter)

    const int  fb = wg >> 2;          // 0..117
    const int  cb = wg & 3;           // 0..3
    const long t0 = (long)fb * BM;
    const int  c0 = cb * 128;

    // Staging sources. chunk c = j*512 + tid: row = j*64 + (tid>>3),
    // source-chunk sc = (tid&7) ^ ((tid>>3)&7)  (j-independent).
    const int sc = (tid & 7) ^ ((tid >> 3) & 7);
    const unsigned short* aS[4];
    #pragma unroll
    for (int j = 0; j < 4; ++j) {
        long tf = t0 + j * 64 + (tid >> 3);
        if (tf > FRAMES - 1) tf = FRAMES - 1;           // only fb=117 clamps
        aS[j] = pad + tf * 512 + sc * 8;
    }
    // B: brow(j) = brow0 + j*32; brow0 = ch0 + (parity? 513:0),
    // ch0 = c0 + (tid>>8)*16 + ((tid>>3)&15), parity = (tid>>7)&1.
    const int ch0 = c0 + ((tid >> 8) << 4) + ((tid >> 3) & 15);
    const long brow0 = ch0 + (((tid >> 7) & 1) ? 513 : 0);
    const unsigned short* bS0 = bas + brow0 * 1024 + sc * 8;

    f32x4 acc[8][4];
    #pragma unroll
    for (int a = 0; a < 8; ++a)
        #pragma unroll
        for (int b = 0; b < 4; ++b)
            acc[a][b] = (f32x4){0.f, 0.f, 0.f, 0.f};

    const int wmBase = wm * 128;
    const int wnBase = wn * 64;

#define GLD(dst, src) __builtin_amdgcn_global_load_lds( \
        (const __attribute__((address_space(1))) unsigned int*)(src), \
        (__attribute__((address_space(3))) unsigned int*)(dst), 16, 0, 0)

#define LDSREAD(basePtr, r, S) \
    (*reinterpret_cast<const short8*>(reinterpret_cast<const char*>(basePtr) \
        + (r) * 128 + ((((S) * 4 + lk) ^ ((r) & 7)) << 4)))

#define MCLUST(AF, MQ) do { \
    __builtin_amdgcn_s_setprio(1); \
    _Pragma("unroll") for (int b_ = 0; b_ < 4; ++b_) \
      _Pragma("unroll") for (int m_ = 0; m_ < 4; ++m_) \
        acc[(MQ)*4+m_][b_] = __builtin_amdgcn_mfma_f32_16x16x32_bf16( \
            AF[m_], bf[b_], acc[(MQ)*4+m_][b_], 0, 0, 0); \
    __builtin_amdgcn_s_setprio(0); } while (0)

    // Prologue: stage tile 0 into buf 0.
    #pragma unroll
    for (int j = 0; j < 4; ++j) {
        GLD(&lsA[0][j * 4096 + tid * 8], aS[j]);
        GLD(&lsB[0][j * 4096 + tid * 8], bS0 + j * 32768);
    }

    short8 afA[4], afB[4], bf[4];

    for (int t = 0; t < NKT; ++t) {
        const int p = t & 1;
        const unsigned short* curA = lsA[p];
        const unsigned short* curB = lsB[p];

        // drains own stage(t) GLDs (vmcnt 0), syncs all waves, memory fence
        __syncthreads();

        // R1+R2: all S=0 fragments (12 ds_reads)
        #pragma unroll
        for (int b = 0; b < 4; ++b) bf[b]  = LDSREAD(curB, wnBase + b * 16 + l15, 0);
        #pragma unroll
        for (int m = 0; m < 4; ++m) afA[m] = LDSREAD(curA, wmBase + m * 16 + l15, 0);
        #pragma unroll
        for (int m = 0; m < 4; ++m) afB[m] = LDSREAD(curA, wmBase + (m + 4) * 16 + l15, 0);

        // stage(t+1) early: full-tile latency cover, opposite buffer (safe:
        // tile t-1's reads of that buffer retired before the sync above).
        if (t + 1 < NKT) {
            const int ko = (t + 1) * BK;
            unsigned short* nA = lsA[p ^ 1];
            unsigned short* nB = lsB[p ^ 1];
            #pragma unroll
            for (int j = 0; j < 4; ++j) {
                GLD(nA + j * 4096 + tid * 8, aS[j] + ko);
                GLD(nB + j * 4096 + tid * 8, bS0 + j * 32768 + ko);
            }
        }
        __builtin_amdgcn_sched_barrier(0);
        MCLUST(afA, 0);                                   // S0, m-frags 0-3 -> acc[0..3]
        __builtin_amdgcn_sched_barrier(0);
        #pragma unroll
        for (int m = 0; m < 4; ++m) afA[m] = LDSREAD(curA, wmBase + m * 16 + l15, 1);
        __builtin_amdgcn_sched_barrier(0);
        MCLUST(afB, 1);                                   // S0, m-frags 4-7 -> acc[4..7]
        __builtin_amdgcn_sched_barrier(0);
        #pragma unroll
        for (int b = 0; b < 4; ++b) bf[b]  = LDSREAD(curB, wnBase + b * 16 + l15, 1);
        #pragma unroll
        for (int m = 0; m < 4; ++m) afB[m] = LDSREAD(curA, wmBase + (m + 4) * 16 + l15, 1);
        __builtin_amdgcn_sched_barrier(0);
        MCLUST(afA, 0);                                   // S1, m-frags 0-3 -> acc[0..3]
        __builtin_amdgcn_sched_barrier(0);
        MCLUST(afB, 1);                                   // S1, m-frags 4-7 -> acc[4..7]
    }

    // Epilogue: out[ch][t] = re^2 + im^2 (ch = 0..511, always valid)
    const int tb = (int)t0 + wmBase;
    #pragma unroll
    for (int a = 0; a < 8; ++a) {
        #pragma unroll
        for (int q = 0; q < 2; ++q) {
            const int ch = c0 + wn * 32 + q * 16 + l15;
            const long ob = (long)ch * FRAMES;
            const int tv = tb + a * 16 + lk * 4;
            const f32x4 re = acc[a][q * 2];
            const f32x4 im = acc[a][q * 2 + 1];
            if (tv + 3 < FRAMES) {
                #pragma unroll
                for (int r = 0; r < 4; ++r)
                    out[ob + tv + r] = re[r] * re[r] + im[r] * im[r];
            } else {
                #pragma unroll
                for (int r = 0; r < 4; ++r)
                    if (tv + r < FRAMES)
                        out[ob + tv + r] = re[r] * re[r] + im[r] * im[r];
            }
        }
    }
}

extern "C" void kernel_launch(void* const* d_in, const int* in_sizes, int n_in,
                              void* d_out, int out_size, void* d_ws, size_t ws_size,
                              hipStream_t stream) {
    const float* audio = (const float*)d_in[0];
    const float* basis = (const float*)d_in[1];
    float* out = (float*)d_out;

    unsigned short* pad = (unsigned short*)d_ws;
    unsigned short* bas = pad + PADLEN;

    prep_pad_k<<<PADLEN / 4 / 256, 256, 0, stream>>>(audio, pad);
    prep_bas_k<<<NBAS / 4 / 256, 256, 0, stream>>>(basis, bas);

    stft_gemm<<<NWG, 512, 0, stream>>>(pad, bas, basis, out);
}